// Round 1
// baseline (1491.744 us; speedup 1.0000x reference)
//
#include <hip/hip_runtime.h>

#define TT 128
#define BB 32
#define NN (TT*BB)   // 4096

typedef float f4 __attribute__((ext_vector_type(4)));
typedef short s8 __attribute__((ext_vector_type(8)));

__device__ __forceinline__ float bf2f(unsigned short u){
  union{unsigned int i; float f;} x; x.i = ((unsigned int)u)<<16; return x.f;
}
__device__ __forceinline__ unsigned short f2bf(float f){
  union{float ff; unsigned int i;} x; x.ff=f;
  unsigned int r = x.i + 0x7FFFu + ((x.i>>16)&1u);
  return (unsigned short)(r>>16);
}

// -------- conv1: x(4096,1,84,84) f32 -> z1(4096,32,20,[24 pad]) bf16, k8 s4, /255, +b, relu
// thread = (n, cog of 4 co, oh, ow-half of 10). 4096*8*20*2 = 1,310,720 threads.
__global__ __launch_bounds__(256) void conv1_k(const float* __restrict__ x,
    const float* __restrict__ W1, const float* __restrict__ b1,
    unsigned short* __restrict__ z1){
  int gid = blockIdx.x*256 + threadIdx.x;
  int n = gid/320; int r = gid - n*320;
  int cog = r/40; r -= cog*40;
  int oh = r>>1; int ow2 = r&1;
  const float* xb = x + (size_t)n*7056 + (size_t)(oh*4)*84 + ow2*40;
  float acc[4][10];
  #pragma unroll
  for(int q=0;q<4;q++)
    #pragma unroll
    for(int o=0;o<10;o++) acc[q][o]=0.f;
  #pragma unroll
  for(int kh=0;kh<8;kh++){
    const float* xr = xb + kh*84;
    float xv[44];
    #pragma unroll
    for(int i=0;i<11;i++){
      f4 v = *(const f4*)(xr + i*4);
      xv[i*4+0]=v[0]; xv[i*4+1]=v[1]; xv[i*4+2]=v[2]; xv[i*4+3]=v[3];
    }
    float wv[4][8];
    #pragma unroll
    for(int q=0;q<4;q++){
      f4 a = *(const f4*)(W1 + (cog*4+q)*64 + kh*8);
      f4 b = *(const f4*)(W1 + (cog*4+q)*64 + kh*8 + 4);
      wv[q][0]=a[0];wv[q][1]=a[1];wv[q][2]=a[2];wv[q][3]=a[3];
      wv[q][4]=b[0];wv[q][5]=b[1];wv[q][6]=b[2];wv[q][7]=b[3];
    }
    #pragma unroll
    for(int q=0;q<4;q++)
      #pragma unroll
      for(int o=0;o<10;o++)
        #pragma unroll
        for(int kw=0;kw<8;kw++)
          acc[q][o] = fmaf(xv[o*4+kw], wv[q][kw], acc[q][o]);
  }
  const float inv255 = 1.f/255.f;
  #pragma unroll
  for(int q=0;q<4;q++){
    int c = cog*4+q;
    float bias = b1[c];
    #pragma unroll
    for(int o=0;o<10;o++){
      float v = bias + acc[q][o]*inv255;
      v = v>0.f? v:0.f;
      z1[((size_t)(n*32+c)*20 + oh)*24 + ow2*10 + o] = f2bf(v);
    }
  }
}

// -------- conv2: z1 bf16 (n,32,20,[24]) -> z2(n,64,9,[16 pad]) bf16, k4 s2, +b2, relu
// thread = (n, cog of 8 co, oh). 4096*8*9 = 294,912 threads.
__global__ __launch_bounds__(256) void conv2_k(const unsigned short* __restrict__ z1,
    const float* __restrict__ W2, const float* __restrict__ b2,
    unsigned short* __restrict__ z2){
  int gid = blockIdx.x*256 + threadIdx.x;
  int n = gid/72; int r = gid - n*72;
  int cog = r/9; int oh = r - cog*9;
  float acc[8][9]={};
  for(int ci=0;ci<32;ci++){
    const unsigned short* zb = z1 + ((size_t)(n*32+ci)*20 + oh*2)*24;
    #pragma unroll
    for(int kh=0;kh<4;kh++){
      const unsigned short* zr = zb + kh*24;
      s8 r0 = *(const s8*)zr; s8 r1 = *(const s8*)(zr+8); s8 r2 = *(const s8*)(zr+16);
      float xr[20];
      #pragma unroll
      for(int e=0;e<8;e++){ xr[e]=bf2f((unsigned short)r0[e]); xr[8+e]=bf2f((unsigned short)r1[e]); }
      #pragma unroll
      for(int e=0;e<4;e++) xr[16+e]=bf2f((unsigned short)r2[e]);
      float wv[8][4];
      #pragma unroll
      for(int q=0;q<8;q++){
        f4 w = *(const f4*)(W2 + ((size_t)(cog*8+q)*32+ci)*16 + kh*4);
        wv[q][0]=w[0]; wv[q][1]=w[1]; wv[q][2]=w[2]; wv[q][3]=w[3];
      }
      #pragma unroll
      for(int q=0;q<8;q++)
        #pragma unroll
        for(int o=0;o<9;o++)
          #pragma unroll
          for(int kw=0;kw<4;kw++)
            acc[q][o] = fmaf(xr[o*2+kw], wv[q][kw], acc[q][o]);
    }
  }
  #pragma unroll
  for(int q=0;q<8;q++){
    int co = cog*8+q; float bias = b2[co];
    #pragma unroll
    for(int o=0;o<9;o++){
      float v = bias + acc[q][o]; v = v>0.f?v:0.f;
      z2[((size_t)(n*64+co)*9+oh)*16 + o] = f2bf(v);
    }
  }
}

// -------- conv3: z2 bf16 (n,64,9,[16]) -> z3(n,3136) bf16 (c*49+y*7+x), k3 s1, +b3, relu
// thread = (n, cog of 8 co, oh). 4096*8*7 = 229,376 threads.
__global__ __launch_bounds__(256) void conv3_k(const unsigned short* __restrict__ z2,
    const float* __restrict__ W3, const float* __restrict__ b3,
    unsigned short* __restrict__ z3){
  int gid = blockIdx.x*256 + threadIdx.x;
  int n = gid/56; int r = gid - n*56;
  int cog = r/7; int oh = r - cog*7;
  float acc[8][7]={};
  for(int ci=0;ci<64;ci++){
    #pragma unroll
    for(int kh=0;kh<3;kh++){
      const unsigned short* zr = z2 + ((size_t)(n*64+ci)*9 + oh+kh)*16;
      s8 a0 = *(const s8*)zr;
      float xr[9];
      #pragma unroll
      for(int e=0;e<8;e++) xr[e]=bf2f((unsigned short)a0[e]);
      xr[8] = bf2f(zr[8]);
      float wv[8][3];
      #pragma unroll
      for(int q=0;q<8;q++){
        const float* wp = W3 + ((size_t)(cog*8+q)*64+ci)*9 + kh*3;
        wv[q][0]=wp[0]; wv[q][1]=wp[1]; wv[q][2]=wp[2];
      }
      #pragma unroll
      for(int q=0;q<8;q++)
        #pragma unroll
        for(int o=0;o<7;o++)
          #pragma unroll
          for(int kw=0;kw<3;kw++)
            acc[q][o] = fmaf(xr[o+kw], wv[q][kw], acc[q][o]);
    }
  }
  #pragma unroll
  for(int q=0;q<8;q++){
    int co = cog*8+q; float bias = b3[co];
    #pragma unroll
    for(int o=0;o<7;o++){
      float v = bias + acc[q][o]; v = v>0.f?v:0.f;
      z3[(size_t)n*3136 + co*49 + oh*7 + o] = f2bf(v);
    }
  }
}

// -------- tiled GEMM: C[M,N] = act(A[M,K] * B[N,K]^T + bias1 (+bias2))
// BM=128, BN=64, BK=16, 256 thr, 8x4 micro-tile. A is bf16 (ABF16=1) or f32.
template<int ABF16>
__global__ __launch_bounds__(256) void gemm_k(const void* __restrict__ Av,
    const float* __restrict__ B, const float* __restrict__ bias1,
    const float* __restrict__ bias2, float* __restrict__ C,
    int M, int N, int K, int do_relu){
  __shared__ float As[16][132];
  __shared__ float Bs[16][68];
  int tid = threadIdx.x;
  int bx = blockIdx.x, by = blockIdx.y;
  int tx = tid & 15, ty = tid >> 4;
  float acc[8][4] = {};
  int ar = tid >> 1, ac8 = (tid & 1)*8;
  int br = tid >> 2, bc4 = (tid & 3)*4;
  const unsigned short* A16 = (const unsigned short*)Av;
  const float* A32 = (const float*)Av;
  for(int k0=0; k0<K; k0+=16){
    if(ABF16){
      s8 av = *(const s8*)(A16 + (size_t)(by*128+ar)*K + k0 + ac8);
      #pragma unroll
      for(int j=0;j<8;j++) As[ac8+j][ar] = bf2f((unsigned short)av[j]);
    } else {
      f4 a0 = *(const f4*)(A32 + (size_t)(by*128+ar)*K + k0 + ac8);
      f4 a1 = *(const f4*)(A32 + (size_t)(by*128+ar)*K + k0 + ac8 + 4);
      #pragma unroll
      for(int j=0;j<4;j++){ As[ac8+j][ar]=a0[j]; As[ac8+4+j][ar]=a1[j]; }
    }
    f4 bv = *(const f4*)(B + (size_t)(bx*64+br)*K + k0 + bc4);
    #pragma unroll
    for(int j=0;j<4;j++) Bs[bc4+j][br] = bv[j];
    __syncthreads();
    #pragma unroll
    for(int kk=0;kk<16;kk++){
      f4 b4 = *(const f4*)&Bs[kk][tx*4];
      f4 a0 = *(const f4*)&As[kk][ty*8];
      f4 a1 = *(const f4*)&As[kk][ty*8+4];
      #pragma unroll
      for(int i=0;i<4;i++)
        #pragma unroll
        for(int j=0;j<4;j++){
          acc[i][j]   = fmaf(a0[i], b4[j], acc[i][j]);
          acc[4+i][j] = fmaf(a1[i], b4[j], acc[4+i][j]);
        }
    }
    __syncthreads();
  }
  #pragma unroll
  for(int j=0;j<4;j++){
    int c = bx*64 + tx*4 + j;
    float bb = bias1[c] + (bias2 ? bias2[c] : 0.f);
    #pragma unroll
    for(int i=0;i<8;i++){
      int rr = by*128 + ty*8 + i;
      float v = acc[i][j] + bb;
      if(do_relu) v = v>0.f?v:0.f;
      C[(size_t)rr*N + c] = v;
    }
  }
}

// -------- LSTM scan: one block per batch element b. 512 threads: thread g owns gate-row g.
// W_hh row in VGPRs; h,c,gates in LDS. gx already includes b_ih+b_hh.
__global__ __launch_bounds__(512) void lstm_k(const float* __restrict__ gx,
    const float* __restrict__ done, const float* __restrict__ h0,
    const float* __restrict__ c0, const float* __restrict__ W_hh,
    float* __restrict__ hs, float* __restrict__ out_hT, float* __restrict__ out_cT){
  int b = blockIdx.x;
  int g = threadIdx.x;
  __shared__ __align__(16) float hS[128];
  __shared__ __align__(16) float cS[128];
  __shared__ __align__(16) float gS[512];
  f4 w[32];
  #pragma unroll
  for(int k=0;k<32;k++) w[k] = *(const f4*)(W_hh + (size_t)g*128 + k*4);
  if(g < 128){ hS[g] = h0[b*128+g]; cS[g] = c0[b*128+g]; }
  __syncthreads();
  for(int t=0;t<TT;t++){
    float mask = 1.f - done[t*BB + b];
    if(g < 128){ hS[g] *= mask; cS[g] *= mask; }
    __syncthreads();
    float acc = gx[(size_t)(t*BB+b)*512 + g];
    #pragma unroll
    for(int k=0;k<32;k++){
      f4 hv = *(const f4*)&hS[k*4];
      acc = fmaf(hv[0], w[k][0], acc);
      acc = fmaf(hv[1], w[k][1], acc);
      acc = fmaf(hv[2], w[k][2], acc);
      acc = fmaf(hv[3], w[k][3], acc);
    }
    gS[g] = acc;
    __syncthreads();
    if(g < 128){
      float ig = gS[g], fg = gS[128+g], gg = gS[256+g], og = gS[384+g];
      float si = 1.f/(1.f+__expf(-ig));
      float sf = 1.f/(1.f+__expf(-fg));
      float so = 1.f/(1.f+__expf(-og));
      float tg = tanhf(gg);
      float cn = sf*cS[g] + si*tg;
      float hn = so*tanhf(cn);
      cS[g]=cn; hS[g]=hn;
      hs[(size_t)(t*BB+b)*128 + g] = hn;
    }
    __syncthreads();
  }
  if(g<128){ out_hT[b*128+g]=hS[g]; out_cT[b*128+g]=cS[g]; }
}

// -------- heads: logits (n,6) + value (n). thread per (n, a) with a in 0..6.
__global__ __launch_bounds__(256) void heads_k(const float* __restrict__ hs,
    const float* __restrict__ Wa, const float* __restrict__ ba,
    const float* __restrict__ Wc, const float* __restrict__ bc,
    float* __restrict__ out){
  int gid = blockIdx.x*256 + threadIdx.x;  // 4096*7
  int n = gid/7, a = gid - n*7;
  const float* w = (a<6) ? (Wa + a*128) : Wc;
  float bias = (a<6) ? ba[a] : bc[0];
  const float* h = hs + (size_t)n*128;
  float acc = 0.f;
  #pragma unroll
  for(int k=0;k<32;k++){
    f4 hv = *(const f4*)(h + k*4);
    f4 wv = *(const f4*)(w + k*4);
    acc += hv[0]*wv[0]+hv[1]*wv[1]+hv[2]*wv[2]+hv[3]*wv[3];
  }
  float v = acc + bias;
  if(a<6) out[(size_t)n*6 + a] = v;
  else    out[24576 + n] = v;
}

extern "C" void kernel_launch(void* const* d_in, const int* in_sizes, int n_in,
                              void* d_out, int out_size, void* d_ws, size_t ws_size,
                              hipStream_t stream){
  const float* x    = (const float*)d_in[0];
  const float* done = (const float*)d_in[1];
  const float* h0   = (const float*)d_in[2];
  const float* c0   = (const float*)d_in[3];
  const float* W1   = (const float*)d_in[4];
  const float* b1   = (const float*)d_in[5];
  const float* W2   = (const float*)d_in[6];
  const float* b2   = (const float*)d_in[7];
  const float* W3   = (const float*)d_in[8];
  const float* b3   = (const float*)d_in[9];
  const float* Wfc  = (const float*)d_in[10];
  const float* bfc  = (const float*)d_in[11];
  const float* W_ih = (const float*)d_in[12];
  const float* W_hh = (const float*)d_in[13];
  const float* b_ih = (const float*)d_in[14];
  const float* b_hh = (const float*)d_in[15];
  const float* Wa   = (const float*)d_in[16];
  const float* ba   = (const float*)d_in[17];
  const float* Wc   = (const float*)d_in[18];
  const float* bc   = (const float*)d_in[19];
  float* out = (float*)d_out;

  char* ws = (char*)d_ws;
  // region plan (bytes): z1 [0,125829120) ; z2 [125829120,201326592)
  // z3 reuses [0,25690112) after conv2 is done with z1; hidden/gx/hs follow z3.
  unsigned short* z1 = (unsigned short*)(ws + 0);
  unsigned short* z2 = (unsigned short*)(ws + 125829120);
  unsigned short* z3 = (unsigned short*)(ws + 0);
  float* hidden = (float*)(ws + 25690112);
  float* gx     = (float*)(ws + 34078720);
  float* hs     = (float*)(ws + 42467328);

  conv1_k<<<5120,256,0,stream>>>(x, W1, b1, z1);
  conv2_k<<<1152,256,0,stream>>>(z1, W2, b2, z2);
  conv3_k<<<896,256,0,stream>>>(z2, W3, b3, z3);
  gemm_k<1><<<dim3(8,32),256,0,stream>>>(z3, Wfc, bfc, nullptr, hidden, NN, 512, 3136, 1);
  gemm_k<0><<<dim3(8,32),256,0,stream>>>(hidden, W_ih, b_ih, b_hh, gx, NN, 512, 512, 0);
  lstm_k<<<32,512,0,stream>>>(gx, done, h0, c0, W_hh, hs, out+28672, out+32768);
  heads_k<<<112,256,0,stream>>>(hs, Wa, ba, Wc, bc, out);
}

// Round 2
// 588.115 us; speedup vs baseline: 2.5365x; 2.5365x over previous
//
#include <hip/hip_runtime.h>

#define TT 128
#define BB 32
#define NN (TT*BB)   // 4096

typedef float f4 __attribute__((ext_vector_type(4)));
typedef float f32x4 __attribute__((ext_vector_type(4)));
typedef short s8 __attribute__((ext_vector_type(8)));
typedef short bf16x8 __attribute__((ext_vector_type(8)));
typedef short s4v __attribute__((ext_vector_type(4)));

__device__ __forceinline__ float bf2f(unsigned short u){
  union{unsigned int i; float f;} x; x.i = ((unsigned int)u)<<16; return x.f;
}
__device__ __forceinline__ unsigned short f2bf(float f){
  union{float ff; unsigned int i;} x; x.ff=f;
  unsigned int r = x.i + 0x7FFFu + ((x.i>>16)&1u);
  return (unsigned short)(r>>16);
}

// ================= weight prep: f32 -> bf16, [N][K] with K in gather order ==
// w2c[co][(kh*4+kw)*32+ci] = W2[co][ci][kh][kw]   (64x512)
__global__ __launch_bounds__(256) void prep_w2(const float* __restrict__ W2,
    unsigned short* __restrict__ w2c){
  int i = blockIdx.x*256 + threadIdx.x;       // 32768
  int co = i >> 9; int rem = i & 511; int khw = rem >> 5; int ci = rem & 31;
  w2c[i] = f2bf(W2[(co*32 + ci)*16 + khw]);
}
// w3c[co][(kh*3+kw)*64+ci] = W3[co][ci][kh][kw]   (64x576)
__global__ __launch_bounds__(256) void prep_w3(const float* __restrict__ W3,
    unsigned short* __restrict__ w3c){
  int i = blockIdx.x*256 + threadIdx.x;       // 36864
  int co = i/576; int rem = i - co*576; int khw = rem >> 6; int ci = rem & 63;
  w3c[i] = f2bf(W3[(co*64 + ci)*9 + khw]);
}
// wfcc[nn][sp*64+ci] = Wfc[nn][ci*49+sp]          (512x3136)
__global__ __launch_bounds__(256) void prep_wfc(const float* __restrict__ Wfc,
    unsigned short* __restrict__ wfcc){
  int i = blockIdx.x*256 + threadIdx.x;       // 1605632
  int nn = i/3136; int rem = i - nn*3136; int sp = rem >> 6; int ci = rem & 63;
  wfcc[i] = f2bf(Wfc[nn*3136 + ci*49 + sp]);
}
// wihc = bf16(W_ih) row-major (512x512)
__global__ __launch_bounds__(256) void prep_wih(const float* __restrict__ W_ih,
    unsigned short* __restrict__ wihc){
  int i = blockIdx.x*256 + threadIdx.x;       // 262144
  wihc[i] = f2bf(W_ih[i]);
}

// ================= conv1: x(4096,1,84,84) f32 -> z1 NHWC (n,20,20,32) bf16 ==
// thread = (n, cog of 4 co, oh, ow-half of 10). 4096*8*20*2 = 1,310,720 threads.
__global__ __launch_bounds__(256) void conv1_k(const float* __restrict__ x,
    const float* __restrict__ W1, const float* __restrict__ b1,
    unsigned short* __restrict__ z1){
  int gid = blockIdx.x*256 + threadIdx.x;
  int n = gid/320; int r = gid - n*320;
  int cog = r/40; r -= cog*40;
  int oh = r>>1; int ow2 = r&1;
  const float* xb = x + (size_t)n*7056 + (size_t)(oh*4)*84 + ow2*40;
  float acc[4][10];
  #pragma unroll
  for(int q=0;q<4;q++)
    #pragma unroll
    for(int o=0;o<10;o++) acc[q][o]=0.f;
  #pragma unroll
  for(int kh=0;kh<8;kh++){
    const float* xr = xb + kh*84;
    float xv[44];
    #pragma unroll
    for(int i=0;i<11;i++){
      f4 v = *(const f4*)(xr + i*4);
      xv[i*4+0]=v[0]; xv[i*4+1]=v[1]; xv[i*4+2]=v[2]; xv[i*4+3]=v[3];
    }
    float wv[4][8];
    #pragma unroll
    for(int q=0;q<4;q++){
      f4 a = *(const f4*)(W1 + (cog*4+q)*64 + kh*8);
      f4 b = *(const f4*)(W1 + (cog*4+q)*64 + kh*8 + 4);
      wv[q][0]=a[0];wv[q][1]=a[1];wv[q][2]=a[2];wv[q][3]=a[3];
      wv[q][4]=b[0];wv[q][5]=b[1];wv[q][6]=b[2];wv[q][7]=b[3];
    }
    #pragma unroll
    for(int q=0;q<4;q++)
      #pragma unroll
      for(int o=0;o<10;o++)
        #pragma unroll
        for(int kw=0;kw<8;kw++)
          acc[q][o] = fmaf(xv[o*4+kw], wv[q][kw], acc[q][o]);
  }
  const float inv255 = 1.f/255.f;
  #pragma unroll
  for(int o=0;o<10;o++){
    s4v pk;
    #pragma unroll
    for(int q=0;q<4;q++){
      float v = b1[cog*4+q] + acc[q][o]*inv255;
      v = v>0.f? v:0.f;
      pk[q] = (short)f2bf(v);
    }
    // z1 NHWC: ((n*20+oh)*20 + ow)*32 + co
    *(s4v*)&z1[(((size_t)n*20+oh)*20 + ow2*10 + o)*32 + cog*4] = pk;
  }
}

// ================= unified MFMA GEMM =======================================
// C[M,N] = act(A[M,K]*B[N,K]^T + bias1 (+bias2)); A bf16 (gathered), B bf16 [N][K].
// BM=128, BN=64, BK=32. 256 threads = 4 waves (2x2), wave tile 64x32.
// MODE 0: plain A rows. MODE 1: conv2 implicit (z1 NHWC 20x20x32, k=(kh,kw,ci), s=khw).
// MODE 2: conv3 implicit (z2 NHWC 9x9x64, k=(kh,kw,ci), s=khw*2+cihalf).
template<int MODE, int OUTBF16, int RELU>
__global__ __launch_bounds__(256) void mgemm_k(
    const unsigned short* __restrict__ A, const unsigned short* __restrict__ B,
    const float* __restrict__ bias1, const float* __restrict__ bias2,
    void* __restrict__ Cout, int K, int Nld){
  __shared__ unsigned short As[128*40];
  __shared__ unsigned short Bs[64*40];
  int t = threadIdx.x;
  int bm = blockIdx.y, bn = blockIdx.x;
  // ---- A staging setup: thread t stages row (t>>1), half (t&1) (16 bf16 = 32B)
  int arow = t >> 1, ahalf = t & 1;
  int gm = bm*128 + arow;
  const unsigned short* abase;
  if(MODE == 0){
    abase = A + (size_t)gm*K + ahalf*16;
  } else if(MODE == 1){
    int n = gm/81; int r = gm - n*81; int oh = r/9; int ow = r - oh*9;
    abase = A + (((size_t)n*20 + 2*oh)*20 + 2*ow)*32 + ahalf*16;
  } else {
    int n = gm/49; int r = gm - n*49; int oh = r/7; int ow = r - oh*7;
    abase = A + (((size_t)n*9 + oh)*9 + ow)*64 + ahalf*16;
  }
  // ---- B staging: thread t stages row (t>>2), quarter (t&3) (8 bf16 = 16B)
  int brow = t >> 2, bq = t & 3;
  const unsigned short* bbase = B + (size_t)(bn*64 + brow)*K + bq*8;
  // ---- wave/lane mfma coords
  int l = t & 63, w = t >> 6;
  int wr = w >> 1, wc = w & 1;
  int lr = l & 15, lk = (l >> 4)*8;
  f32x4 acc[4][2] = {};
  int nsteps = K >> 5;
  for(int s=0; s<nsteps; s++){
    // stage A
    const unsigned short* src;
    if(MODE == 0){
      src = abase + s*32;
    } else if(MODE == 1){
      int kh = s >> 2, kw = s & 3;
      src = abase + (kh*20 + kw)*32;
    } else {
      int khw = s >> 1; int kh = khw/3; int kw = khw - kh*3;
      src = abase + (kh*9 + kw)*64 + (s & 1)*32;
    }
    bf16x8 a0 = *(const bf16x8*)src;
    bf16x8 a1 = *(const bf16x8*)(src + 8);
    *(bf16x8*)&As[arow*40 + ahalf*16] = a0;
    *(bf16x8*)&As[arow*40 + ahalf*16 + 8] = a1;
    // stage B
    bf16x8 bv = *(const bf16x8*)(bbase + s*32);
    *(bf16x8*)&Bs[brow*40 + bq*8] = bv;
    __syncthreads();
    // compute
    bf16x8 af[4];
    #pragma unroll
    for(int mf=0; mf<4; mf++)
      af[mf] = *(const bf16x8*)&As[(wr*64 + mf*16 + lr)*40 + lk];
    bf16x8 b0 = *(const bf16x8*)&Bs[(wc*32 + lr)*40 + lk];
    bf16x8 b1 = *(const bf16x8*)&Bs[(wc*32 + 16 + lr)*40 + lk];
    #pragma unroll
    for(int mf=0; mf<4; mf++){
      acc[mf][0] = __builtin_amdgcn_mfma_f32_16x16x32_bf16(af[mf], b0, acc[mf][0], 0, 0, 0);
      acc[mf][1] = __builtin_amdgcn_mfma_f32_16x16x32_bf16(af[mf], b1, acc[mf][1], 0, 0, 0);
    }
    __syncthreads();
  }
  // ---- epilogue: C row = (lane>>4)*4+reg within frag, col = lane&15
  #pragma unroll
  for(int nf=0; nf<2; nf++){
    int gcol = bn*64 + wc*32 + nf*16 + lr;
    float bb = bias1[gcol] + (bias2 ? bias2[gcol] : 0.f);
    #pragma unroll
    for(int mf=0; mf<4; mf++){
      #pragma unroll
      for(int reg=0; reg<4; reg++){
        int grow = bm*128 + wr*64 + mf*16 + (l>>4)*4 + reg;
        float v = acc[mf][nf][reg] + bb;
        if(RELU) v = v>0.f ? v : 0.f;
        if(OUTBF16) ((unsigned short*)Cout)[(size_t)grow*Nld + gcol] = f2bf(v);
        else        ((float*)Cout)[(size_t)grow*Nld + gcol] = v;
      }
    }
  }
}

// ================= LSTM scan ===============================================
__global__ __launch_bounds__(512) void lstm_k(const float* __restrict__ gx,
    const float* __restrict__ done, const float* __restrict__ h0,
    const float* __restrict__ c0, const float* __restrict__ W_hh,
    float* __restrict__ hs, float* __restrict__ out_hT, float* __restrict__ out_cT){
  int b = blockIdx.x;
  int g = threadIdx.x;
  __shared__ __align__(16) float hS[128];
  __shared__ __align__(16) float cS[128];
  __shared__ __align__(16) float gS[512];
  f4 w[32];
  #pragma unroll
  for(int k=0;k<32;k++) w[k] = *(const f4*)(W_hh + (size_t)g*128 + k*4);
  if(g < 128){ hS[g] = h0[b*128+g]; cS[g] = c0[b*128+g]; }
  __syncthreads();
  for(int t=0;t<TT;t++){
    float mask = 1.f - done[t*BB + b];
    if(g < 128){ hS[g] *= mask; cS[g] *= mask; }
    __syncthreads();
    float acc = gx[(size_t)(t*BB+b)*512 + g];
    #pragma unroll
    for(int k=0;k<32;k++){
      f4 hv = *(const f4*)&hS[k*4];
      acc = fmaf(hv[0], w[k][0], acc);
      acc = fmaf(hv[1], w[k][1], acc);
      acc = fmaf(hv[2], w[k][2], acc);
      acc = fmaf(hv[3], w[k][3], acc);
    }
    gS[g] = acc;
    __syncthreads();
    if(g < 128){
      float ig = gS[g], fg = gS[128+g], gg = gS[256+g], og = gS[384+g];
      float si = 1.f/(1.f+__expf(-ig));
      float sf = 1.f/(1.f+__expf(-fg));
      float so = 1.f/(1.f+__expf(-og));
      float tg = tanhf(gg);
      float cn = sf*cS[g] + si*tg;
      float hn = so*tanhf(cn);
      cS[g]=cn; hS[g]=hn;
      hs[(size_t)(t*BB+b)*128 + g] = hn;
    }
    __syncthreads();
  }
  if(g<128){ out_hT[b*128+g]=hS[g]; out_cT[b*128+g]=cS[g]; }
}

// ================= heads ===================================================
__global__ __launch_bounds__(256) void heads_k(const float* __restrict__ hs,
    const float* __restrict__ Wa, const float* __restrict__ ba,
    const float* __restrict__ Wc, const float* __restrict__ bc,
    float* __restrict__ out){
  int gid = blockIdx.x*256 + threadIdx.x;  // 4096*7
  int n = gid/7, a = gid - n*7;
  const float* w = (a<6) ? (Wa + a*128) : Wc;
  float bias = (a<6) ? ba[a] : bc[0];
  const float* h = hs + (size_t)n*128;
  float acc = 0.f;
  #pragma unroll
  for(int k=0;k<32;k++){
    f4 hv = *(const f4*)(h + k*4);
    f4 wv = *(const f4*)(w + k*4);
    acc += hv[0]*wv[0]+hv[1]*wv[1]+hv[2]*wv[2]+hv[3]*wv[3];
  }
  float v = acc + bias;
  if(a<6) out[(size_t)n*6 + a] = v;
  else    out[24576 + n] = v;
}

extern "C" void kernel_launch(void* const* d_in, const int* in_sizes, int n_in,
                              void* d_out, int out_size, void* d_ws, size_t ws_size,
                              hipStream_t stream){
  const float* x    = (const float*)d_in[0];
  const float* done = (const float*)d_in[1];
  const float* h0   = (const float*)d_in[2];
  const float* c0   = (const float*)d_in[3];
  const float* W1   = (const float*)d_in[4];
  const float* b1   = (const float*)d_in[5];
  const float* W2   = (const float*)d_in[6];
  const float* b2   = (const float*)d_in[7];
  const float* W3   = (const float*)d_in[8];
  const float* b3   = (const float*)d_in[9];
  const float* Wfc  = (const float*)d_in[10];
  const float* bfc  = (const float*)d_in[11];
  const float* W_ih = (const float*)d_in[12];
  const float* W_hh = (const float*)d_in[13];
  const float* b_ih = (const float*)d_in[14];
  const float* b_hh = (const float*)d_in[15];
  const float* Wa   = (const float*)d_in[16];
  const float* ba   = (const float*)d_in[17];
  const float* Wc   = (const float*)d_in[18];
  const float* bc   = (const float*)d_in[19];
  float* out = (float*)d_out;

  char* ws = (char*)d_ws;
  // region plan (bytes):
  //  z1 NHWC  [0, 104857600)            (n,20,20,32) bf16
  //  z2 NHWC  [104857600, 147324928)    (n,9,9,64)  bf16
  //  z3 NHWC  [0, 25690112)             reuses z1 (dead after conv2)
  //  hidden   [25690112, 29884416)      (4096,512) bf16
  //  gx       [29884416, 38273024)      (4096,512) f32
  //  hs       [38273024, 40370176)      (4096,128) f32
  //  w2c [147324928, +65536) w3c [147390464, +73728)
  //  wfcc [147464192, +3211264) wihc [150675456, +524288) end 151199744
  unsigned short* z1   = (unsigned short*)(ws + 0);
  unsigned short* z2   = (unsigned short*)(ws + 104857600);
  unsigned short* z3   = (unsigned short*)(ws + 0);
  unsigned short* hid  = (unsigned short*)(ws + 25690112);
  float* gx            = (float*)(ws + 29884416);
  float* hs            = (float*)(ws + 38273024);
  unsigned short* w2c  = (unsigned short*)(ws + 147324928);
  unsigned short* w3c  = (unsigned short*)(ws + 147390464);
  unsigned short* wfcc = (unsigned short*)(ws + 147464192);
  unsigned short* wihc = (unsigned short*)(ws + 150675456);

  prep_w2 <<<128, 256, 0, stream>>>(W2, w2c);
  prep_w3 <<<144, 256, 0, stream>>>(W3, w3c);
  prep_wfc<<<6272,256, 0, stream>>>(Wfc, wfcc);
  prep_wih<<<1024,256, 0, stream>>>(W_ih, wihc);

  conv1_k<<<5120,256,0,stream>>>(x, W1, b1, z1);
  // conv2: M=4096*81=331776, N=64, K=512
  mgemm_k<1,1,1><<<dim3(1,2592),256,0,stream>>>(z1, w2c, b2, nullptr, z2, 512, 64);
  // conv3: M=4096*49=200704, N=64, K=576
  mgemm_k<2,1,1><<<dim3(1,1568),256,0,stream>>>(z2, w3c, b3, nullptr, z3, 576, 64);
  // FC: M=4096, N=512, K=3136 -> hidden bf16 (relu)
  mgemm_k<0,1,1><<<dim3(8,32),256,0,stream>>>(z3, wfcc, bfc, nullptr, hid, 3136, 512);
  // gates: M=4096, N=512, K=512 -> gx f32, bias b_ih+b_hh
  mgemm_k<0,0,0><<<dim3(8,32),256,0,stream>>>(hid, wihc, b_ih, b_hh, gx, 512, 512);

  lstm_k<<<32,512,0,stream>>>(gx, done, h0, c0, W_hh, hs, out+28672, out+32768);
  heads_k<<<112,256,0,stream>>>(hs, Wa, ba, Wc, bc, out);
}

// Round 3
// 443.470 us; speedup vs baseline: 3.3638x; 1.3262x over previous
//
#include <hip/hip_runtime.h>

#define TT 128
#define BB 32
#define NN (TT*BB)   // 4096

typedef float f4 __attribute__((ext_vector_type(4)));
typedef float f32x4 __attribute__((ext_vector_type(4)));
typedef short s8 __attribute__((ext_vector_type(8)));
typedef short bf16x8 __attribute__((ext_vector_type(8)));
typedef short s4v __attribute__((ext_vector_type(4)));

__device__ __forceinline__ float bf2f(unsigned short u){
  union{unsigned int i; float f;} x; x.i = ((unsigned int)u)<<16; return x.f;
}
__device__ __forceinline__ unsigned short f2bf(float f){
  union{float ff; unsigned int i;} x; x.ff=f;
  unsigned int r = x.i + 0x7FFFu + ((x.i>>16)&1u);
  return (unsigned short)(r>>16);
}

// ================= weight prep: f32 -> bf16, [N][K] with K in gather order ==
// w1c[co][kh*8+kw] = W1[co][0][kh][kw]/255, zero-padded to 64 rows (64x64)
__global__ __launch_bounds__(256) void prep_w1(const float* __restrict__ W1,
    unsigned short* __restrict__ w1c){
  int i = blockIdx.x*256 + threadIdx.x;       // 4096
  int co = i >> 6; int k = i & 63;
  w1c[i] = (co < 32) ? f2bf(W1[co*64 + k] * (1.f/255.f)) : (unsigned short)0;
}
// w2c[co][(kh*4+kw)*32+ci] = W2[co][ci][kh][kw]   (64x512)
__global__ __launch_bounds__(256) void prep_w2(const float* __restrict__ W2,
    unsigned short* __restrict__ w2c){
  int i = blockIdx.x*256 + threadIdx.x;       // 32768
  int co = i >> 9; int rem = i & 511; int khw = rem >> 5; int ci = rem & 31;
  w2c[i] = f2bf(W2[(co*32 + ci)*16 + khw]);
}
// w3c[co][(kh*3+kw)*64+ci] = W3[co][ci][kh][kw]   (64x576)
__global__ __launch_bounds__(256) void prep_w3(const float* __restrict__ W3,
    unsigned short* __restrict__ w3c){
  int i = blockIdx.x*256 + threadIdx.x;       // 36864
  int co = i/576; int rem = i - co*576; int khw = rem >> 6; int ci = rem & 63;
  w3c[i] = f2bf(W3[(co*64 + ci)*9 + khw]);
}
// wfcc[nn][sp*64+ci] = Wfc[nn][ci*49+sp]          (512x3136)
__global__ __launch_bounds__(256) void prep_wfc(const float* __restrict__ Wfc,
    unsigned short* __restrict__ wfcc){
  int i = blockIdx.x*256 + threadIdx.x;       // 1605632
  int nn = i/3136; int rem = i - nn*3136; int sp = rem >> 6; int ci = rem & 63;
  wfcc[i] = f2bf(Wfc[nn*3136 + ci*49 + sp]);
}
// wihc = bf16(W_ih) row-major (512x512)
__global__ __launch_bounds__(256) void prep_wih(const float* __restrict__ W_ih,
    unsigned short* __restrict__ wihc){
  int i = blockIdx.x*256 + threadIdx.x;       // 262144
  wihc[i] = f2bf(W_ih[i]);
}
// x f32 (4096,84,84) -> bf16 (values 0..255; /255 folded into w1c)
__global__ __launch_bounds__(256) void prep_x(const float* __restrict__ x,
    unsigned short* __restrict__ xb){
  int i = blockIdx.x*256 + threadIdx.x;       // 3,612,672 (28,901,376/8)
  f4 v0 = *(const f4*)(x + (size_t)i*8);
  f4 v1 = *(const f4*)(x + (size_t)i*8 + 4);
  s8 o;
  #pragma unroll
  for(int j=0;j<4;j++){ o[j] = (short)f2bf(v0[j]); o[4+j] = (short)f2bf(v1[j]); }
  *(s8*)&xb[(size_t)i*8] = o;
}

// ================= unified MFMA GEMM =======================================
// C[M,N] = act(A[M,K]*B[N,K]^T + bias1 (+bias2)); A bf16 (gathered), B bf16 [N][K].
// BM=128, BN=64, BK=32. 256 threads = 4 waves (2x2), wave tile 64x32.
// MODE 0: plain A rows.
// MODE 1: conv2 implicit (z1 NHWC 20x20x32, k=(kh,kw,ci), s=khw).
// MODE 2: conv3 implicit (z2 NHWC 9x9x64, k=(kh,kw,ci), s=khw*2+cihalf).
// MODE 3: conv1 implicit (xb16 (n,84,84), k=kh*8+kw, stride 4, patch 8x8).
template<int MODE, int OUTBF16, int RELU>
__global__ __launch_bounds__(256) void mgemm_k(
    const unsigned short* __restrict__ A, const unsigned short* __restrict__ B,
    const float* __restrict__ bias1, const float* __restrict__ bias2,
    void* __restrict__ Cout, int K, int Nld, int nout){
  __shared__ unsigned short As[128*40];
  __shared__ unsigned short Bs[64*40];
  int t = threadIdx.x;
  int bm = blockIdx.y, bn = blockIdx.x;
  // ---- A staging setup: thread t stages row (t>>1), half (t&1) (16 bf16 = 32B)
  int arow = t >> 1, ahalf = t & 1;
  int gm = bm*128 + arow;
  const unsigned short* abase;
  if(MODE == 0){
    abase = A + (size_t)gm*K + ahalf*16;
  } else if(MODE == 1){
    int n = gm/81; int r = gm - n*81; int oh = r/9; int ow = r - oh*9;
    abase = A + (((size_t)n*20 + 2*oh)*20 + 2*ow)*32 + ahalf*16;
  } else if(MODE == 2){
    int n = gm/49; int r = gm - n*49; int oh = r/7; int ow = r - oh*7;
    abase = A + (((size_t)n*9 + oh)*9 + ow)*64 + ahalf*16;
  } else {
    int n = gm/400; int r = gm - n*400; int oh = r/20; int ow = r - oh*20;
    abase = A + (size_t)n*7056 + (size_t)(oh*4)*84 + ow*4;  // patch origin
  }
  // ---- B staging: thread t stages row (t>>2), quarter (t&3) (8 bf16 = 16B)
  int brow = t >> 2, bq = t & 3;
  const unsigned short* bbase = B + (size_t)(bn*64 + brow)*K + bq*8;
  // ---- wave/lane mfma coords
  int l = t & 63, w = t >> 6;
  int wr = w >> 1, wc = w & 1;
  int lr = l & 15, lk = (l >> 4)*8;
  f32x4 acc[4][2] = {};
  int nsteps = K >> 5;
  for(int s=0; s<nsteps; s++){
    // stage A
    if(MODE == 3){
      // k = s*32 + ahalf*16 + j ; kh = s*4 + ahalf*2 + (j>>3), kw = j&7
      const unsigned short* src = abase + (size_t)(s*4 + ahalf*2)*84;
      s4v p0 = *(const s4v*)src;
      s4v p1 = *(const s4v*)(src + 4);
      s4v p2 = *(const s4v*)(src + 84);
      s4v p3 = *(const s4v*)(src + 88);
      *(s4v*)&As[arow*40 + ahalf*16]      = p0;
      *(s4v*)&As[arow*40 + ahalf*16 + 4]  = p1;
      *(s4v*)&As[arow*40 + ahalf*16 + 8]  = p2;
      *(s4v*)&As[arow*40 + ahalf*16 + 12] = p3;
    } else {
      const unsigned short* src;
      if(MODE == 0){
        src = abase + s*32;
      } else if(MODE == 1){
        int kh = s >> 2, kw = s & 3;
        src = abase + (kh*20 + kw)*32;
      } else {
        int khw = s >> 1; int kh = khw/3; int kw = khw - kh*3;
        src = abase + (kh*9 + kw)*64 + (s & 1)*32;
      }
      bf16x8 a0 = *(const bf16x8*)src;
      bf16x8 a1 = *(const bf16x8*)(src + 8);
      *(bf16x8*)&As[arow*40 + ahalf*16] = a0;
      *(bf16x8*)&As[arow*40 + ahalf*16 + 8] = a1;
    }
    // stage B
    bf16x8 bv = *(const bf16x8*)(bbase + s*32);
    *(bf16x8*)&Bs[brow*40 + bq*8] = bv;
    __syncthreads();
    // compute
    bf16x8 af[4];
    #pragma unroll
    for(int mf=0; mf<4; mf++)
      af[mf] = *(const bf16x8*)&As[(wr*64 + mf*16 + lr)*40 + lk];
    bf16x8 b0 = *(const bf16x8*)&Bs[(wc*32 + lr)*40 + lk];
    bf16x8 b1 = *(const bf16x8*)&Bs[(wc*32 + 16 + lr)*40 + lk];
    #pragma unroll
    for(int mf=0; mf<4; mf++){
      acc[mf][0] = __builtin_amdgcn_mfma_f32_16x16x32_bf16(af[mf], b0, acc[mf][0], 0, 0, 0);
      acc[mf][1] = __builtin_amdgcn_mfma_f32_16x16x32_bf16(af[mf], b1, acc[mf][1], 0, 0, 0);
    }
    __syncthreads();
  }
  // ---- epilogue: C row = (lane>>4)*4+reg within frag, col = lane&15
  #pragma unroll
  for(int nf=0; nf<2; nf++){
    int gcol = bn*64 + wc*32 + nf*16 + lr;
    if(gcol >= nout) continue;
    float bb = bias1[gcol] + (bias2 ? bias2[gcol] : 0.f);
    #pragma unroll
    for(int mf=0; mf<4; mf++){
      #pragma unroll
      for(int reg=0; reg<4; reg++){
        int grow = bm*128 + wr*64 + mf*16 + (l>>4)*4 + reg;
        float v = acc[mf][nf][reg] + bb;
        if(RELU) v = v>0.f ? v : 0.f;
        if(OUTBF16) ((unsigned short*)Cout)[(size_t)grow*Nld + gcol] = f2bf(v);
        else        ((float*)Cout)[(size_t)grow*Nld + gcol] = v;
      }
    }
  }
}

// ================= LSTM scan ===============================================
__global__ __launch_bounds__(512) void lstm_k(const float* __restrict__ gx,
    const float* __restrict__ done, const float* __restrict__ h0,
    const float* __restrict__ c0, const float* __restrict__ W_hh,
    float* __restrict__ hs, float* __restrict__ out_hT, float* __restrict__ out_cT){
  int b = blockIdx.x;
  int g = threadIdx.x;
  __shared__ __align__(16) float hS[128];
  __shared__ __align__(16) float cS[128];
  __shared__ __align__(16) float gS[512];
  f4 w[32];
  #pragma unroll
  for(int k=0;k<32;k++) w[k] = *(const f4*)(W_hh + (size_t)g*128 + k*4);
  if(g < 128){ hS[g] = h0[b*128+g]; cS[g] = c0[b*128+g]; }
  __syncthreads();
  for(int t=0;t<TT;t++){
    float mask = 1.f - done[t*BB + b];
    if(g < 128){ hS[g] *= mask; cS[g] *= mask; }
    __syncthreads();
    float acc = gx[(size_t)(t*BB+b)*512 + g];
    #pragma unroll
    for(int k=0;k<32;k++){
      f4 hv = *(const f4*)&hS[k*4];
      acc = fmaf(hv[0], w[k][0], acc);
      acc = fmaf(hv[1], w[k][1], acc);
      acc = fmaf(hv[2], w[k][2], acc);
      acc = fmaf(hv[3], w[k][3], acc);
    }
    gS[g] = acc;
    __syncthreads();
    if(g < 128){
      float ig = gS[g], fg = gS[128+g], gg = gS[256+g], og = gS[384+g];
      float si = 1.f/(1.f+__expf(-ig));
      float sf = 1.f/(1.f+__expf(-fg));
      float so = 1.f/(1.f+__expf(-og));
      float tg = tanhf(gg);
      float cn = sf*cS[g] + si*tg;
      float hn = so*tanhf(cn);
      cS[g]=cn; hS[g]=hn;
      hs[(size_t)(t*BB+b)*128 + g] = hn;
    }
    __syncthreads();
  }
  if(g<128){ out_hT[b*128+g]=hS[g]; out_cT[b*128+g]=cS[g]; }
}

// ================= heads ===================================================
__global__ __launch_bounds__(256) void heads_k(const float* __restrict__ hs,
    const float* __restrict__ Wa, const float* __restrict__ ba,
    const float* __restrict__ Wc, const float* __restrict__ bc,
    float* __restrict__ out){
  int gid = blockIdx.x*256 + threadIdx.x;  // 4096*7
  int n = gid/7, a = gid - n*7;
  const float* w = (a<6) ? (Wa + a*128) : Wc;
  float bias = (a<6) ? ba[a] : bc[0];
  const float* h = hs + (size_t)n*128;
  float acc = 0.f;
  #pragma unroll
  for(int k=0;k<32;k++){
    f4 hv = *(const f4*)(h + k*4);
    f4 wv = *(const f4*)(w + k*4);
    acc += hv[0]*wv[0]+hv[1]*wv[1]+hv[2]*wv[2]+hv[3]*wv[3];
  }
  float v = acc + bias;
  if(a<6) out[(size_t)n*6 + a] = v;
  else    out[24576 + n] = v;
}

extern "C" void kernel_launch(void* const* d_in, const int* in_sizes, int n_in,
                              void* d_out, int out_size, void* d_ws, size_t ws_size,
                              hipStream_t stream){
  const float* x    = (const float*)d_in[0];
  const float* done = (const float*)d_in[1];
  const float* h0   = (const float*)d_in[2];
  const float* c0   = (const float*)d_in[3];
  const float* W1   = (const float*)d_in[4];
  const float* b1   = (const float*)d_in[5];
  const float* W2   = (const float*)d_in[6];
  const float* b2   = (const float*)d_in[7];
  const float* W3   = (const float*)d_in[8];
  const float* b3   = (const float*)d_in[9];
  const float* Wfc  = (const float*)d_in[10];
  const float* bfc  = (const float*)d_in[11];
  const float* W_ih = (const float*)d_in[12];
  const float* W_hh = (const float*)d_in[13];
  const float* b_ih = (const float*)d_in[14];
  const float* b_hh = (const float*)d_in[15];
  const float* Wa   = (const float*)d_in[16];
  const float* ba   = (const float*)d_in[17];
  const float* Wc   = (const float*)d_in[18];
  const float* bc   = (const float*)d_in[19];
  float* out = (float*)d_out;

  char* ws = (char*)d_ws;
  // region plan (bytes), stream-ordered reuse:
  //  z1 NHWC   [0, 104857600)             (n,20,20,32) bf16   [conv1 -> conv2]
  //  xb16      [104857600, 162660352)     (n,84,84) bf16      [prep_x -> conv1]
  //  z2 NHWC   [104857600, 147324928)     (n,9,9,64) bf16     [conv2 -> conv3] (reuses dead xb16)
  //  z3 NHWC   [0, 25690112)              (n,7,7,64) bf16     [conv3 -> FC]    (reuses dead z1)
  //  hid       [25690112, 29884416)       (4096,512) bf16
  //  gx        [29884416, 38273024)       (4096,512) f32
  //  hs        [38273024, 40370176)       (4096,128) f32
  //  weights   [162660352, ...) : w2c +65536, w3c +73728, wfcc +3211264,
  //            wihc +524288, w1c +8192  -> end 166543360
  unsigned short* z1   = (unsigned short*)(ws + 0);
  unsigned short* xb16 = (unsigned short*)(ws + 104857600);
  unsigned short* z2   = (unsigned short*)(ws + 104857600);
  unsigned short* z3   = (unsigned short*)(ws + 0);
  unsigned short* hid  = (unsigned short*)(ws + 25690112);
  float* gx            = (float*)(ws + 29884416);
  float* hs            = (float*)(ws + 38273024);
  unsigned short* w2c  = (unsigned short*)(ws + 162660352);
  unsigned short* w3c  = (unsigned short*)(ws + 162725888);
  unsigned short* wfcc = (unsigned short*)(ws + 162799616);
  unsigned short* wihc = (unsigned short*)(ws + 166010880);
  unsigned short* w1c  = (unsigned short*)(ws + 166535168);

  prep_w1 <<<16,  256, 0, stream>>>(W1, w1c);
  prep_w2 <<<128, 256, 0, stream>>>(W2, w2c);
  prep_w3 <<<144, 256, 0, stream>>>(W3, w3c);
  prep_wfc<<<6272,256, 0, stream>>>(Wfc, wfcc);
  prep_wih<<<1024,256, 0, stream>>>(W_ih, wihc);
  prep_x  <<<14112,256,0, stream>>>(x, xb16);

  // conv1: M=4096*400=1638400, N=32 (padded 64), K=64
  mgemm_k<3,1,1><<<dim3(1,12800),256,0,stream>>>(xb16, w1c, b1, nullptr, z1, 64, 32, 32);
  // conv2: M=4096*81=331776, N=64, K=512
  mgemm_k<1,1,1><<<dim3(1,2592),256,0,stream>>>(z1, w2c, b2, nullptr, z2, 512, 64, 64);
  // conv3: M=4096*49=200704, N=64, K=576
  mgemm_k<2,1,1><<<dim3(1,1568),256,0,stream>>>(z2, w3c, b3, nullptr, z3, 576, 64, 64);
  // FC: M=4096, N=512, K=3136 -> hidden bf16 (relu)
  mgemm_k<0,1,1><<<dim3(8,32),256,0,stream>>>(z3, wfcc, bfc, nullptr, hid, 3136, 512, 512);
  // gates: M=4096, N=512, K=512 -> gx f32, bias b_ih+b_hh
  mgemm_k<0,0,0><<<dim3(8,32),256,0,stream>>>(hid, wihc, b_ih, b_hh, gx, 512, 512, 512);

  lstm_k<<<32,512,0,stream>>>(gx, done, h0, c0, W_hh, hs, out+28672, out+32768);
  heads_k<<<112,256,0,stream>>>(hs, Wa, ba, Wc, bc, out);
}

// Round 4
// 430.046 us; speedup vs baseline: 3.4688x; 1.0312x over previous
//
#include <hip/hip_runtime.h>

#define TT 128
#define BB 32
#define NN (TT*BB)   // 4096

typedef float f4 __attribute__((ext_vector_type(4)));
typedef float f32x4 __attribute__((ext_vector_type(4)));
typedef short s8 __attribute__((ext_vector_type(8)));
typedef short bf16x8 __attribute__((ext_vector_type(8)));
typedef short s4v __attribute__((ext_vector_type(4)));

__device__ __forceinline__ float bf2f(unsigned short u){
  union{unsigned int i; float f;} x; x.i = ((unsigned int)u)<<16; return x.f;
}
__device__ __forceinline__ unsigned short f2bf(float f){
  union{float ff; unsigned int i;} x; x.ff=f;
  unsigned int r = x.i + 0x7FFFu + ((x.i>>16)&1u);
  return (unsigned short)(r>>16);
}
// NaN-safe fast sigmoid/tanh (exp->inf handled by rcp(inf)=0)
__device__ __forceinline__ float fsig(float x){
  return __builtin_amdgcn_rcpf(1.f + __expf(-x));
}
__device__ __forceinline__ float ftanh(float x){
  return 1.f - 2.f*__builtin_amdgcn_rcpf(1.f + __expf(2.f*x));
}

// ================= weight prep: f32 -> bf16, [N][K] with K in gather order ==
__global__ __launch_bounds__(256) void prep_w1(const float* __restrict__ W1,
    unsigned short* __restrict__ w1c){
  int i = blockIdx.x*256 + threadIdx.x;       // 4096
  int co = i >> 6; int k = i & 63;
  w1c[i] = (co < 32) ? f2bf(W1[co*64 + k] * (1.f/255.f)) : (unsigned short)0;
}
__global__ __launch_bounds__(256) void prep_w2(const float* __restrict__ W2,
    unsigned short* __restrict__ w2c){
  int i = blockIdx.x*256 + threadIdx.x;       // 32768
  int co = i >> 9; int rem = i & 511; int khw = rem >> 5; int ci = rem & 31;
  w2c[i] = f2bf(W2[(co*32 + ci)*16 + khw]);
}
__global__ __launch_bounds__(256) void prep_w3(const float* __restrict__ W3,
    unsigned short* __restrict__ w3c){
  int i = blockIdx.x*256 + threadIdx.x;       // 36864
  int co = i/576; int rem = i - co*576; int khw = rem >> 6; int ci = rem & 63;
  w3c[i] = f2bf(W3[(co*64 + ci)*9 + khw]);
}
__global__ __launch_bounds__(256) void prep_wfc(const float* __restrict__ Wfc,
    unsigned short* __restrict__ wfcc){
  int i = blockIdx.x*256 + threadIdx.x;       // 1605632
  int nn = i/3136; int rem = i - nn*3136; int sp = rem >> 6; int ci = rem & 63;
  wfcc[i] = f2bf(Wfc[nn*3136 + ci*49 + sp]);
}
__global__ __launch_bounds__(256) void prep_wih(const float* __restrict__ W_ih,
    unsigned short* __restrict__ wihc){
  int i = blockIdx.x*256 + threadIdx.x;       // 262144
  wihc[i] = f2bf(W_ih[i]);
}
// W_hh (512,128) f32 -> bf16 row-major
__global__ __launch_bounds__(256) void prep_whh(const float* __restrict__ W_hh,
    unsigned short* __restrict__ whhc){
  int i = blockIdx.x*256 + threadIdx.x;       // 65536
  whhc[i] = f2bf(W_hh[i]);
}
// x f32 -> bf16
__global__ __launch_bounds__(256) void prep_x(const float* __restrict__ x,
    unsigned short* __restrict__ xb){
  int i = blockIdx.x*256 + threadIdx.x;       // 3,612,672
  f4 v0 = *(const f4*)(x + (size_t)i*8);
  f4 v1 = *(const f4*)(x + (size_t)i*8 + 4);
  s8 o;
  #pragma unroll
  for(int j=0;j<4;j++){ o[j] = (short)f2bf(v0[j]); o[4+j] = (short)f2bf(v1[j]); }
  *(s8*)&xb[(size_t)i*8] = o;
}

// ================= unified MFMA GEMM =======================================
// C[M,N] = act(A[M,K]*B[N,K]^T + bias1 (+bias2)); A bf16 (gathered), B bf16 [N][K].
// BM=128, BN=64, BK=32. 256 threads = 4 waves (2x2), wave tile 64x32.
// MODE 0: plain A rows. MODE 1: conv2 implicit. MODE 2: conv3 implicit.
// MODE 3: conv1 implicit. TRANSGX: store f32 C transposed as [t][col][batch] f32x4.
template<int MODE, int OUTBF16, int RELU, int TRANSGX>
__global__ __launch_bounds__(256) void mgemm_k(
    const unsigned short* __restrict__ A, const unsigned short* __restrict__ B,
    const float* __restrict__ bias1, const float* __restrict__ bias2,
    void* __restrict__ Cout, int K, int Nld, int nout){
  __shared__ unsigned short As[128*40];
  __shared__ unsigned short Bs[64*40];
  int t = threadIdx.x;
  int bm = blockIdx.y, bn = blockIdx.x;
  int arow = t >> 1, ahalf = t & 1;
  int gm = bm*128 + arow;
  const unsigned short* abase;
  if(MODE == 0){
    abase = A + (size_t)gm*K + ahalf*16;
  } else if(MODE == 1){
    int n = gm/81; int r = gm - n*81; int oh = r/9; int ow = r - oh*9;
    abase = A + (((size_t)n*20 + 2*oh)*20 + 2*ow)*32 + ahalf*16;
  } else if(MODE == 2){
    int n = gm/49; int r = gm - n*49; int oh = r/7; int ow = r - oh*7;
    abase = A + (((size_t)n*9 + oh)*9 + ow)*64 + ahalf*16;
  } else {
    int n = gm/400; int r = gm - n*400; int oh = r/20; int ow = r - oh*20;
    abase = A + (size_t)n*7056 + (size_t)(oh*4)*84 + ow*4;
  }
  int brow = t >> 2, bq = t & 3;
  const unsigned short* bbase = B + (size_t)(bn*64 + brow)*K + bq*8;
  int l = t & 63, w = t >> 6;
  int wr = w >> 1, wc = w & 1;
  int lr = l & 15, lk = (l >> 4)*8;
  f32x4 acc[4][2] = {};
  int nsteps = K >> 5;
  for(int s=0; s<nsteps; s++){
    if(MODE == 3){
      const unsigned short* src = abase + (size_t)(s*4 + ahalf*2)*84;
      s4v p0 = *(const s4v*)src;
      s4v p1 = *(const s4v*)(src + 4);
      s4v p2 = *(const s4v*)(src + 84);
      s4v p3 = *(const s4v*)(src + 88);
      *(s4v*)&As[arow*40 + ahalf*16]      = p0;
      *(s4v*)&As[arow*40 + ahalf*16 + 4]  = p1;
      *(s4v*)&As[arow*40 + ahalf*16 + 8]  = p2;
      *(s4v*)&As[arow*40 + ahalf*16 + 12] = p3;
    } else {
      const unsigned short* src;
      if(MODE == 0){
        src = abase + s*32;
      } else if(MODE == 1){
        int kh = s >> 2, kw = s & 3;
        src = abase + (kh*20 + kw)*32;
      } else {
        int khw = s >> 1; int kh = khw/3; int kw = khw - kh*3;
        src = abase + (kh*9 + kw)*64 + (s & 1)*32;
      }
      bf16x8 a0 = *(const bf16x8*)src;
      bf16x8 a1 = *(const bf16x8*)(src + 8);
      *(bf16x8*)&As[arow*40 + ahalf*16] = a0;
      *(bf16x8*)&As[arow*40 + ahalf*16 + 8] = a1;
    }
    bf16x8 bv = *(const bf16x8*)(bbase + s*32);
    *(bf16x8*)&Bs[brow*40 + bq*8] = bv;
    __syncthreads();
    bf16x8 af[4];
    #pragma unroll
    for(int mf=0; mf<4; mf++)
      af[mf] = *(const bf16x8*)&As[(wr*64 + mf*16 + lr)*40 + lk];
    bf16x8 b0 = *(const bf16x8*)&Bs[(wc*32 + lr)*40 + lk];
    bf16x8 b1 = *(const bf16x8*)&Bs[(wc*32 + 16 + lr)*40 + lk];
    #pragma unroll
    for(int mf=0; mf<4; mf++){
      acc[mf][0] = __builtin_amdgcn_mfma_f32_16x16x32_bf16(af[mf], b0, acc[mf][0], 0, 0, 0);
      acc[mf][1] = __builtin_amdgcn_mfma_f32_16x16x32_bf16(af[mf], b1, acc[mf][1], 0, 0, 0);
    }
    __syncthreads();
  }
  #pragma unroll
  for(int nf=0; nf<2; nf++){
    int gcol = bn*64 + wc*32 + nf*16 + lr;
    if(gcol >= nout) continue;
    float bb = bias1[gcol] + (bias2 ? bias2[gcol] : 0.f);
    if(TRANSGX){
      int grow0 = bm*128 + wr*64 + 0 + (l>>4)*4;
      #pragma unroll
      for(int mf=0; mf<4; mf++){
        int grow = grow0 + mf*16;
        int tt = grow >> 5, b = grow & 31;
        f4 v;
        #pragma unroll
        for(int reg=0; reg<4; reg++) v[reg] = acc[mf][nf][reg] + bb;
        *(f4*)&((float*)Cout)[((size_t)tt*512 + gcol)*32 + b] = v;
      }
    } else {
      #pragma unroll
      for(int mf=0; mf<4; mf++){
        #pragma unroll
        for(int reg=0; reg<4; reg++){
          int grow = bm*128 + wr*64 + mf*16 + (l>>4)*4 + reg;
          float v = acc[mf][nf][reg] + bb;
          if(RELU) v = v>0.f ? v : 0.f;
          if(OUTBF16) ((unsigned short*)Cout)[(size_t)grow*Nld + gcol] = f2bf(v);
          else        ((float*)Cout)[(size_t)grow*Nld + gcol] = v;
        }
      }
    }
  }
}

// ================= LSTM scan, MFMA =========================================
// 2 blocks x 512 threads; block handles 16 batch elems. Wave w owns h-units
// [16w,16w+16) across ALL 4 gates -> i,f,g,o land in same lane's accs.
// W_hh frags in VGPRs; h double-buffered bf16 in LDS; gx prefetched from
// transposed layout gxT[t][gatecol][batch].
__global__ __launch_bounds__(512) void lstm_mfma_k(
    const float* __restrict__ gxT, const float* __restrict__ done,
    const float* __restrict__ h0, const float* __restrict__ c0,
    const unsigned short* __restrict__ whhc,
    float* __restrict__ hs, float* __restrict__ out_hT, float* __restrict__ out_cT){
  __shared__ float done_lds[2048];                 // [t][16 batch]
  __shared__ unsigned short hA[2][16][152];        // [buf][batch][unit], pad 152
  int t0 = threadIdx.x;
  int B0 = blockIdx.x * 16;
  int w = t0 >> 6, l = t0 & 63;
  int lr = l & 15, lg = l >> 4;
  int ucol = 16*w + lr;
  // W_hh B-fragments (gate g, k-tile kt): rows = gate cols, cols = h units
  bf16x8 wB[4][4];
  #pragma unroll
  for(int g=0; g<4; g++)
    #pragma unroll
    for(int kt=0; kt<4; kt++)
      wB[g][kt] = *(const bf16x8*)&whhc[(size_t)(g*128 + ucol)*128 + kt*32 + lg*8];
  // stage done
  for(int i=t0; i<2048; i+=512){
    int tt = i >> 4, bb = i & 15;
    done_lds[i] = done[tt*32 + B0 + bb];
  }
  __syncthreads();
  // init h (mask[0] applied), c raw
  float c[4], hl[4];
  #pragma unroll
  for(int r=0; r<4; r++){
    int bi = lg*4 + r;
    float m0 = 1.f - done_lds[bi];
    c[r] = c0[(size_t)(B0+bi)*128 + ucol];
    float h = h0[(size_t)(B0+bi)*128 + ucol];
    hA[0][bi][ucol] = f2bf(h * m0);
  }
  f4 gxc[4], gxn[4];
  #pragma unroll
  for(int g=0; g<4; g++)
    gxc[g] = *(const f4*)&gxT[(size_t)(g*128 + ucol)*32 + B0 + lg*4];
  __syncthreads();

  for(int t=0; t<TT; t++){
    int cur = t & 1;
    // A frags: row = batch (lr), k = units
    bf16x8 aF[4];
    #pragma unroll
    for(int kt=0; kt<4; kt++)
      aF[kt] = *(const bf16x8*)&hA[cur][lr][kt*32 + lg*8];
    // prefetch next-step gx
    if(t < TT-1){
      #pragma unroll
      for(int g=0; g<4; g++)
        gxn[g] = *(const f4*)&gxT[((size_t)(t+1)*512 + g*128 + ucol)*32 + B0 + lg*4];
    }
    f32x4 acc[4];
    #pragma unroll
    for(int g=0; g<4; g++) acc[g] = gxc[g];
    #pragma unroll
    for(int kt=0; kt<4; kt++)
      #pragma unroll
      for(int g=0; g<4; g++)
        acc[g] = __builtin_amdgcn_mfma_f32_16x16x32_bf16(aF[kt], wB[g][kt], acc[g], 0, 0, 0);
    // tail: per lane 4 batches x 1 unit, all in registers
    f4 dn  = *(const f4*)&done_lds[t*16 + lg*4];
    f4 dn2 = dn;
    if(t < TT-1) dn2 = *(const f4*)&done_lds[(t+1)*16 + lg*4];
    #pragma unroll
    for(int r=0; r<4; r++){
      int bi = lg*4 + r;
      float cm = c[r] * (1.f - dn[r]);
      float iv = fsig(acc[0][r]);
      float fv = fsig(acc[1][r]);
      float gv = ftanh(acc[2][r]);
      float ov = fsig(acc[3][r]);
      float cn = fv*cm + iv*gv;
      float hn = ov*ftanh(cn);
      c[r] = cn; hl[r] = hn;
      hs[((size_t)t*32 + B0 + bi)*128 + ucol] = hn;
      if(t < TT-1) hA[cur^1][bi][ucol] = f2bf(hn * (1.f - dn2[r]));
    }
    #pragma unroll
    for(int g=0; g<4; g++) gxc[g] = gxn[g];
    __syncthreads();
  }
  #pragma unroll
  for(int r=0; r<4; r++){
    int bi = lg*4 + r;
    out_hT[(size_t)(B0+bi)*128 + ucol] = hl[r];
    out_cT[(size_t)(B0+bi)*128 + ucol] = c[r];
  }
}

// ================= heads ===================================================
__global__ __launch_bounds__(256) void heads_k(const float* __restrict__ hs,
    const float* __restrict__ Wa, const float* __restrict__ ba,
    const float* __restrict__ Wc, const float* __restrict__ bc,
    float* __restrict__ out){
  int gid = blockIdx.x*256 + threadIdx.x;  // 4096*7
  int n = gid/7, a = gid - n*7;
  const float* w = (a<6) ? (Wa + a*128) : Wc;
  float bias = (a<6) ? ba[a] : bc[0];
  const float* h = hs + (size_t)n*128;
  float acc = 0.f;
  #pragma unroll
  for(int k=0;k<32;k++){
    f4 hv = *(const f4*)(h + k*4);
    f4 wv = *(const f4*)(w + k*4);
    acc += hv[0]*wv[0]+hv[1]*wv[1]+hv[2]*wv[2]+hv[3]*wv[3];
  }
  float v = acc + bias;
  if(a<6) out[(size_t)n*6 + a] = v;
  else    out[24576 + n] = v;
}

extern "C" void kernel_launch(void* const* d_in, const int* in_sizes, int n_in,
                              void* d_out, int out_size, void* d_ws, size_t ws_size,
                              hipStream_t stream){
  const float* x    = (const float*)d_in[0];
  const float* done = (const float*)d_in[1];
  const float* h0   = (const float*)d_in[2];
  const float* c0   = (const float*)d_in[3];
  const float* W1   = (const float*)d_in[4];
  const float* b1   = (const float*)d_in[5];
  const float* W2   = (const float*)d_in[6];
  const float* b2   = (const float*)d_in[7];
  const float* W3   = (const float*)d_in[8];
  const float* b3   = (const float*)d_in[9];
  const float* Wfc  = (const float*)d_in[10];
  const float* bfc  = (const float*)d_in[11];
  const float* W_ih = (const float*)d_in[12];
  const float* W_hh = (const float*)d_in[13];
  const float* b_ih = (const float*)d_in[14];
  const float* b_hh = (const float*)d_in[15];
  const float* Wa   = (const float*)d_in[16];
  const float* ba   = (const float*)d_in[17];
  const float* Wc   = (const float*)d_in[18];
  const float* bc   = (const float*)d_in[19];
  float* out = (float*)d_out;

  char* ws = (char*)d_ws;
  // region plan (bytes), stream-ordered reuse:
  //  z1 NHWC   [0, 104857600)           xb16 [104857600, 162660352)
  //  z2 NHWC   [104857600, 147324928)   (reuses dead xb16)
  //  z3 NHWC   [0, 25690112)            (reuses dead z1)
  //  hid       [25690112, 29884416)
  //  gxT       [29884416, 38273024)     [t][gatecol][batch] f32
  //  hs        [38273024, 40370176)
  //  weights   [162660352,...): w2c +64K, w3c +72K, wfcc +3136K, wihc +512K,
  //            w1c +8K, whhc +128K  -> end 166674432
  unsigned short* z1   = (unsigned short*)(ws + 0);
  unsigned short* xb16 = (unsigned short*)(ws + 104857600);
  unsigned short* z2   = (unsigned short*)(ws + 104857600);
  unsigned short* z3   = (unsigned short*)(ws + 0);
  unsigned short* hid  = (unsigned short*)(ws + 25690112);
  float* gxT           = (float*)(ws + 29884416);
  float* hs            = (float*)(ws + 38273024);
  unsigned short* w2c  = (unsigned short*)(ws + 162660352);
  unsigned short* w3c  = (unsigned short*)(ws + 162725888);
  unsigned short* wfcc = (unsigned short*)(ws + 162799616);
  unsigned short* wihc = (unsigned short*)(ws + 166010880);
  unsigned short* w1c  = (unsigned short*)(ws + 166535168);
  unsigned short* whhc = (unsigned short*)(ws + 166543360);

  prep_w1 <<<16,  256, 0, stream>>>(W1, w1c);
  prep_w2 <<<128, 256, 0, stream>>>(W2, w2c);
  prep_w3 <<<144, 256, 0, stream>>>(W3, w3c);
  prep_wfc<<<6272,256, 0, stream>>>(Wfc, wfcc);
  prep_wih<<<1024,256, 0, stream>>>(W_ih, wihc);
  prep_whh<<<256, 256, 0, stream>>>(W_hh, whhc);
  prep_x  <<<14112,256,0, stream>>>(x, xb16);

  // conv1: M=4096*400, N=32(pad 64), K=64
  mgemm_k<3,1,1,0><<<dim3(1,12800),256,0,stream>>>(xb16, w1c, b1, nullptr, z1, 64, 32, 32);
  // conv2: M=4096*81, N=64, K=512
  mgemm_k<1,1,1,0><<<dim3(1,2592),256,0,stream>>>(z1, w2c, b2, nullptr, z2, 512, 64, 64);
  // conv3: M=4096*49, N=64, K=576
  mgemm_k<2,1,1,0><<<dim3(1,1568),256,0,stream>>>(z2, w3c, b3, nullptr, z3, 576, 64, 64);
  // FC: M=4096, N=512, K=3136 -> hid bf16 relu
  mgemm_k<0,1,1,0><<<dim3(8,32),256,0,stream>>>(z3, wfcc, bfc, nullptr, hid, 3136, 512, 512);
  // gates: M=4096, N=512, K=512 -> gxT f32 transposed [t][col][batch]
  mgemm_k<0,0,0,1><<<dim3(8,32),256,0,stream>>>(hid, wihc, b_ih, b_hh, gxT, 512, 512, 512);

  lstm_mfma_k<<<2,512,0,stream>>>(gxT, done, h0, c0, whhc, hs, out+28672, out+32768);
  heads_k<<<112,256,0,stream>>>(hs, Wa, ba, Wc, bc, out);
}